// Round 1
// 139.053 us; speedup vs baseline: 1.0505x; 1.0505x over previous
//
#include <hip/hip_runtime.h>
#include <math.h>

#define N_EL    16
#define N_NUC   4
#define N_FEATS 32
#define N_PAIRS 184
#define HIDDEN  64
#define TB      32           // batch elements per block
#define BLOCK   256
#define DLD     185          // dist LDS stride
#define H1LD    68           // h1 stride in kernel 2
#define TPW     23           // K-tiles (2 pairs each) per wave; 4*23*2 = 184
#define WS_PART_OFF (1 << 19)   // partials start at 512 KB into d_ws

typedef int   intx8    __attribute__((ext_vector_type(8)));
typedef float floatx16 __attribute__((ext_vector_type(16)));

// triu_indices(16, 1)
__constant__ unsigned char c_I[120] = {
    0,0,0,0,0,0,0,0,0,0,0,0,0,0,0,
    1,1,1,1,1,1,1,1,1,1,1,1,1,1,
    2,2,2,2,2,2,2,2,2,2,2,2,2,
    3,3,3,3,3,3,3,3,3,3,3,3,
    4,4,4,4,4,4,4,4,4,4,4,
    5,5,5,5,5,5,5,5,5,5,
    6,6,6,6,6,6,6,6,6,
    7,7,7,7,7,7,7,7,
    8,8,8,8,8,8,8,
    9,9,9,9,9,9,
    10,10,10,10,10,
    11,11,11,11,
    12,12,12,
    13,13,
    14
};
__constant__ unsigned char c_J[120] = {
    1,2,3,4,5,6,7,8,9,10,11,12,13,14,15,
    2,3,4,5,6,7,8,9,10,11,12,13,14,15,
    3,4,5,6,7,8,9,10,11,12,13,14,15,
    4,5,6,7,8,9,10,11,12,13,14,15,
    5,6,7,8,9,10,11,12,13,14,15,
    6,7,8,9,10,11,12,13,14,15,
    7,8,9,10,11,12,13,14,15,
    8,9,10,11,12,13,14,15,
    9,10,11,12,13,14,15,
    10,11,12,13,14,15,
    11,12,13,14,15,
    12,13,14,15,
    13,14,15,
    14,15,
    15
};

__device__ __forceinline__ float ssp(float x) {
    float a = fabsf(x);
    return fmaxf(x, 0.0f) + log1pf(__expf(-a)) - 0.69314718056f;
}
__device__ __forceinline__ float redg(float v) {
    v += __shfl_xor(v, 1);
    v += __shfl_xor(v, 2);
    v += __shfl_xor(v, 4);
    return v;
}

// ---------------------------------------------------------------------------
// Prep (verified R14): W1 -> fp8 e4m3 (pre-scaled 2^6; MFMA applies 2^-6 via
// scale_b) in 32x32x64 B-fragment order.
// ---------------------------------------------------------------------------
__global__ __launch_bounds__(256)
void prep_w1_kernel(const float* __restrict__ W1, intx8* __restrict__ ws)
{
    __shared__ float w[2 * N_FEATS * HIDDEN];   // 16 KB: two pairs' rows
    const int t = blockIdx.x;
    const float* src = W1 + (size_t)(2 * t) * (N_FEATS * HIDDEN);
    for (int k = threadIdx.x; k < 2 * N_FEATS * HIDDEN; k += 256) w[k] = src[k];
    __syncthreads();

    const int tid = threadIdx.x;
    if (tid >= 128) return;
    const int lane = tid & 63;
    const int nh   = tid >> 6;
    const int lh   = lane >> 5;
    const int col  = nh * 32 + (lane & 31);
    const int fb   = lh * 16;
    intx8 frag;
#pragma unroll
    for (int r = 0; r < 8; ++r) {
        const int pair = r >> 2;
        const int fo   = fb + ((r & 3) << 2);
        const float v0 = 64.0f * w[(pair * N_FEATS + fo + 0) * 64 + col];
        const float v1 = 64.0f * w[(pair * N_FEATS + fo + 1) * 64 + col];
        const float v2 = 64.0f * w[(pair * N_FEATS + fo + 2) * 64 + col];
        const float v3 = 64.0f * w[(pair * N_FEATS + fo + 3) * 64 + col];
        int d = __builtin_amdgcn_cvt_pk_fp8_f32(v0, v1, 0, false);
        d     = __builtin_amdgcn_cvt_pk_fp8_f32(v2, v3, d, true);
        frag[r] = d;
    }
    ws[(size_t)(t * 2 + nh) * 64 + lane] = frag;
}

// ---------------------------------------------------------------------------
// Kernel 1 — GEMM ONLY (R15 split): phases 1-2 + fp8 K-loop, then each wave
// dumps its raw 32x64 partial to global.
// R16: feature gen without v_exp. The feature is consumed as fp8 e4m3, whose
// bit pattern for exp2(y), y<=0, is byte = round(56 + 8y) up to the format's
// own mantissa-linearization error (<=+6.1%, ~= the e4m3 quantization step).
// With t' = sqrt(8)*t:  z = fma(t', -t', 56.5);  byte = sat_u32(z).
// v_cvt_u32_f32 saturates negatives to 0 (far-tail features flush to fp8 0).
// Replaces {fma, mul, v_exp(trans 1/4-rate), 1/2 cvt_pk_fp8} per feature with
// {fma, fma, cvt_u32, 3/4 lshl_or} -> ~2x fewer VALU cycles, zero trans ops.
// ---------------------------------------------------------------------------
__global__ __launch_bounds__(BLOCK)
void wfnet_gemm(const float* __restrict__ rs,
                const float* __restrict__ coords,
                const intx8* __restrict__ ws,
                float* __restrict__ partials)
{
    __shared__ float lds_rs[TB * N_EL * 3];   // 6 KB
    __shared__ float lds_dist[TB * DLD];      // 23.7 KB

    const int tid  = threadIdx.x;
    const int wave = tid >> 6;               // = kh
    const int lane = tid & 63;
    const int m    = lane & 31;
    const int lh   = lane >> 5;

    // ---- phase 1: stage rs ----
    {
        const float* rs_blk = rs + (size_t)blockIdx.x * (TB * N_EL * 3);
        for (int k = tid; k < TB * N_EL * 3; k += BLOCK) lds_rs[k] = rs_blk[k];
    }
    __syncthreads();

    // ---- phase 2: distances only (asy moved to kernel 2) ----
    {
        const int bl = tid >> 3, g = tid & 7;
        const float* myrs = lds_rs + bl * (N_EL * 3);
        float* dst = lds_dist + bl * DLD;
        for (int i = 0; i < 8; ++i) {
            const int p = g + 8 * i;
            const int e = p >> 2, n = p & 3;
            const float dx = myrs[e * 3 + 0] - coords[n * 3 + 0];
            const float dy = myrs[e * 3 + 1] - coords[n * 3 + 1];
            const float dz = myrs[e * 3 + 2] - coords[n * 3 + 2];
            dst[p] = sqrtf(dx * dx + dy * dy + dz * dz);
        }
        for (int i = 0; i < 15; ++i) {
            const int q  = g + 8 * i;
            const int ei = 3 * (int)c_I[q], ej = 3 * (int)c_J[q];
            const float dx = myrs[ei + 0] - myrs[ej + 0];
            const float dy = myrs[ei + 1] - myrs[ej + 1];
            const float dz = myrs[ei + 2] - myrs[ej + 2];
            dst[64 + q] = sqrtf(dx * dx + dy * dy + dz * dz);
        }
    }
    __syncthreads();

    // per-lane Gaussian constants for feats lh*16 .. lh*16+15
    // P1 = sqrt(8*log2(e)) / sigma = 3.3972871404 * 7/(1+10q)
    // so that t'^2 = 8 * log2(e) * ((d-mu)/sigma)^2 and byte = 56.5 - t'^2.
    const int f0 = lh * 16;
#define MKC(P, FF) float P##1, P##0; { \
    const float fq = (float)(FF) * (1.0f / 31.0f); \
    const float mu = 10.0f * fq * fq; \
    const float is = 7.0f / (1.0f + 10.0f * fq); \
    P##1 = is * 3.3972871404442143f; \
    P##0 = -mu * P##1; }
    MKC(F0_,  f0 + 0)  MKC(F1_,  f0 + 1)  MKC(F2_,  f0 + 2)  MKC(F3_,  f0 + 3)
    MKC(F4_,  f0 + 4)  MKC(F5_,  f0 + 5)  MKC(F6_,  f0 + 6)  MKC(F7_,  f0 + 7)
    MKC(F8_,  f0 + 8)  MKC(F9_,  f0 + 9)  MKC(F10_, f0 + 10) MKC(F11_, f0 + 11)
    MKC(F12_, f0 + 12) MKC(F13_, f0 + 13) MKC(F14_, f0 + 14) MKC(F15_, f0 + 15)
#undef MKC

    floatx16 accA = {};
    floatx16 accB = {};
    const intx8* wq = ws + ((size_t)(wave * TPW) * 128 + lane);
    const float* drow = lds_dist + m * DLD + wave * (2 * TPW);

    // e4m3 byte of exp2(-(t')^2 / 8), built directly: sat_u32(56.5 - t'^2).
#define XB(dd, P) ({ \
    const float t_ = fmaf(dd, P##1, P##0); \
    const float z_ = fmaf(t_, -t_, 56.5f); \
    unsigned u_; \
    asm("v_cvt_u32_f32 %0, %1" : "=v"(u_) : "v"(z_)); \
    u_; })
#define PK4(dd, A, B, C, D) \
    (int)(XB(dd, A) | (XB(dd, B) << 8) | (XB(dd, C) << 16) | (XB(dd, D) << 24))
#define MKA8(AV, dx0, dx1) \
    intx8 AV; { \
    AV[0] = PK4(dx0, F0_,  F1_,  F2_,  F3_);  \
    AV[1] = PK4(dx0, F4_,  F5_,  F6_,  F7_);  \
    AV[2] = PK4(dx0, F8_,  F9_,  F10_, F11_); \
    AV[3] = PK4(dx0, F12_, F13_, F14_, F15_); \
    AV[4] = PK4(dx1, F0_,  F1_,  F2_,  F3_);  \
    AV[5] = PK4(dx1, F4_,  F5_,  F6_,  F7_);  \
    AV[6] = PK4(dx1, F8_,  F9_,  F10_, F11_); \
    AV[7] = PK4(dx1, F12_, F13_, F14_, F15_); }
#define KROUND(AV, Q0, Q1) { \
    accA = __builtin_amdgcn_mfma_scale_f32_32x32x64_f8f6f4( \
               AV, Q0, accA, 0, 0, 0, 0x7F7F7F7F, 0, 0x79797979); \
    accB = __builtin_amdgcn_mfma_scale_f32_32x32x64_f8f6f4( \
               AV, Q1, accB, 0, 0, 0, 0x7F7F7F7F, 0, 0x79797979); }

    intx8 pA0 = wq[0],   pA1 = wq[64];
    intx8 pB0 = wq[128], pB1 = wq[192];
    float dA0 = drow[0], dA1 = drow[1];
    float dB0 = drow[2], dB1 = drow[3];

    for (int it = 0; it < 10; ++it) {
        const intx8* wn = wq + 256;
        const float eA0 = drow[4 * it + 4], eA1 = drow[4 * it + 5];
        const float eB0 = drow[4 * it + 6], eB1 = drow[4 * it + 7];

        { MKA8(av, dA0, dA1) KROUND(av, pA0, pA1) }
        pA0 = wn[0]; pA1 = wn[64];

        { MKA8(bv, dB0, dB1) KROUND(bv, pB0, pB1) }
        pB0 = wn[128]; pB1 = wn[192];

        wq = wn;
        dA0 = eA0; dA1 = eA1; dB0 = eB0; dB1 = eB1;
    }
    {
        const intx8* wn = wq + 256;
        const float eA0 = drow[44], eA1 = drow[45];
        { MKA8(av, dA0, dA1) KROUND(av, pA0, pA1) }
        pA0 = wn[0]; pA1 = wn[64];
        { MKA8(bv, dB0, dB1) KROUND(bv, pB0, pB1) }
        { MKA8(cv, eA0, eA1) KROUND(cv, pA0, pA1) }
    }
#undef KROUND
#undef MKA8
#undef PK4
#undef XB

    // ---- dump raw partial to global, no barrier. C/D layout:
    //      col = lane&31 (+32 for B), row el = (rg&3) + 8*(rg>>2) + 4*lh ----
    float* pdst = partials + ((size_t)blockIdx.x * 4 + wave) * 2048;
#pragma unroll
    for (int rg = 0; rg < 16; ++rg) {
        const int el = (rg & 3) + 8 * (rg >> 2) + 4 * lh;
        pdst[el * 64 + m]      = accA[rg];
        pdst[el * 64 + 32 + m] = accB[rg];
    }
}

// ---------------------------------------------------------------------------
// Kernel 2 — tail: sum 4 partials + b1 + ssp -> h1 (LDS) -> layers 2/3 +
// asy (nuc dists recomputed) + output. Low VGPR/LDS -> high occupancy.
// ---------------------------------------------------------------------------
__global__ __launch_bounds__(BLOCK)
void wfnet_tail(const float* __restrict__ rs,
                const float* __restrict__ coords,
                const float* __restrict__ charges,
                const float* __restrict__ partials,
                const float* __restrict__ b1,
                const float* __restrict__ W2,
                const float* __restrict__ b2,
                const float* __restrict__ W3,
                const float* __restrict__ b3,
                float* __restrict__ out)
{
    __shared__ float lds_rs[TB * N_EL * 3];   // 6 KB
    __shared__ float lds_h1[TB * H1LD];       // 8.7 KB

    const int tid = threadIdx.x;
    const int el  = tid >> 3;                // 0..31
    const int g   = tid & 7;
    const int b   = blockIdx.x * TB + el;

    // stage rs for asy
    {
        const float* rs_blk = rs + (size_t)blockIdx.x * (TB * N_EL * 3);
        for (int k = tid; k < TB * N_EL * 3; k += BLOCK) lds_rs[k] = rs_blk[k];
    }

    // sum 4 wave-partials for (el, cols g*8..g*8+7), + b1, ssp -> LDS h1
    {
        const float* pb = partials + (size_t)blockIdx.x * 8192 + el * 64 + g * 8;
        const float4 p00 = ((const float4*)(pb + 0 * 2048))[0];
        const float4 p01 = ((const float4*)(pb + 0 * 2048))[1];
        const float4 p10 = ((const float4*)(pb + 1 * 2048))[0];
        const float4 p11 = ((const float4*)(pb + 1 * 2048))[1];
        const float4 p20 = ((const float4*)(pb + 2 * 2048))[0];
        const float4 p21 = ((const float4*)(pb + 2 * 2048))[1];
        const float4 p30 = ((const float4*)(pb + 3 * 2048))[0];
        const float4 p31 = ((const float4*)(pb + 3 * 2048))[1];
        const float4 ba = ((const float4*)(b1 + g * 8))[0];
        const float4 bb = ((const float4*)(b1 + g * 8))[1];
        float* h1w = lds_h1 + el * H1LD + g * 8;
        h1w[0] = ssp(p00.x + p10.x + p20.x + p30.x + ba.x);
        h1w[1] = ssp(p00.y + p10.y + p20.y + p30.y + ba.y);
        h1w[2] = ssp(p00.z + p10.z + p20.z + p30.z + ba.z);
        h1w[3] = ssp(p00.w + p10.w + p20.w + p30.w + ba.w);
        h1w[4] = ssp(p01.x + p11.x + p21.x + p31.x + bb.x);
        h1w[5] = ssp(p01.y + p11.y + p21.y + p31.y + bb.y);
        h1w[6] = ssp(p01.z + p11.z + p21.z + p31.z + bb.z);
        h1w[7] = ssp(p01.w + p11.w + p21.w + p31.w + bb.w);
    }

    // asy partial: this thread's 8 el-nuc pairs (needs only lds_rs)
    float asy = 0.0f;
    __syncthreads();   // rs staged AND h1 visible
    {
        const float* myrs = lds_rs + el * (N_EL * 3);
        const float4 ch = *(const float4*)charges;
#pragma unroll
        for (int i = 0; i < 8; ++i) {
            const int p = g + 8 * i;
            const int e = p >> 2, n = p & 3;
            const float dx = myrs[e * 3 + 0] - coords[n * 3 + 0];
            const float dy = myrs[e * 3 + 1] - coords[n * 3 + 1];
            const float dz = myrs[e * 3 + 2] - coords[n * 3 + 2];
            const float d = sqrtf(dx * dx + dy * dy + dz * dz);
            const float Z = (n < 2) ? ((n == 0) ? ch.x : ch.y)
                                    : ((n == 2) ? ch.z : ch.w);
            asy += (Z * d + d * d) / (1.0f + d);   // decay = sqrt(2*0.5) = 1
        }
    }
    asy = redg(asy);

    // layers 2/3 (R14-verified structure)
    const float4* __restrict__ W2v = (const float4*)W2;
    const float4* __restrict__ b2v = (const float4*)b2;
    const int wbi = g * 2;
    const float4 b2a = b2v[wbi], b2b = b2v[wbi + 1];
    float s0 = b2a.x, s1 = b2a.y, s2 = b2a.z, s3 = b2a.w;
    float s4 = b2b.x, s5 = b2b.y, s6 = b2b.z, s7 = b2b.w;

    const float* __restrict__ h1row = lds_h1 + el * H1LD;
    for (int k = 0; k < HIDDEN; ++k) {
        const float hk  = h1row[k];
        const float4 wa = W2v[k * 16 + wbi];
        const float4 wb = W2v[k * 16 + wbi + 1];
        s0 = fmaf(hk, wa.x, s0); s1 = fmaf(hk, wa.y, s1);
        s2 = fmaf(hk, wa.z, s2); s3 = fmaf(hk, wa.w, s3);
        s4 = fmaf(hk, wb.x, s4); s5 = fmaf(hk, wb.y, s5);
        s6 = fmaf(hk, wb.z, s6); s7 = fmaf(hk, wb.w, s7);
    }

    const float4* __restrict__ W3v = (const float4*)W3;
    const float4 w3a = W3v[wbi], w3b = W3v[wbi + 1];
    float part = ssp(s0) * w3a.x + ssp(s1) * w3a.y
               + ssp(s2) * w3a.z + ssp(s3) * w3a.w
               + ssp(s4) * w3b.x + ssp(s5) * w3b.y
               + ssp(s6) * w3b.z + ssp(s7) * w3b.w;
    part = redg(part);

    if (g == 0) {
        const float ys = part + b3[0];
        out[b] = __expf(ys) * __expf(-asy);
    }
}

extern "C" void kernel_launch(void* const* d_in, const int* in_sizes, int n_in,
                              void* d_out, int out_size, void* d_ws, size_t ws_size,
                              hipStream_t stream) {
    const float* rs      = (const float*)d_in[0];
    const float* coords  = (const float*)d_in[1];
    const float* charges = (const float*)d_in[2];
    const float* W1      = (const float*)d_in[3];
    const float* b1      = (const float*)d_in[4];
    const float* W2      = (const float*)d_in[5];
    const float* b2      = (const float*)d_in[6];
    const float* W3      = (const float*)d_in[7];
    const float* b3      = (const float*)d_in[8];
    float* out = (float*)d_out;

    const int batch = in_sizes[0] / (N_EL * 3);   // 32768
    intx8* w1f8     = (intx8*)d_ws;               // 368 KB fp8 W1
    float* partials = (float*)((char*)d_ws + WS_PART_OFF);  // 32 MB

    prep_w1_kernel<<<N_PAIRS / 2, 256, 0, stream>>>(W1, w1f8);
    wfnet_gemm<<<batch / TB, BLOCK, 0, stream>>>(rs, coords, w1f8, partials);
    wfnet_tail<<<batch / TB, BLOCK, 0, stream>>>(rs, coords, charges, partials,
                                                 b1, W2, b2, W3, b3, out);
}

// Round 3
// 130.633 us; speedup vs baseline: 1.1182x; 1.0645x over previous
//
#include <hip/hip_runtime.h>
#include <math.h>

#define N_EL    16
#define N_NUC   4
#define N_FEATS 32
#define N_PAIRS 184
#define HIDDEN  64
#define TB      32           // batch elements per block
#define BLOCK   256
#define DLD     185          // dist LDS stride
#define H1LD    68           // h1 stride in kernel 2
#define TPW     23           // K-tiles (2 pairs each) per wave; 4*23*2 = 184
#define WS_PART_OFF (1 << 19)   // partials start at 512 KB into d_ws

typedef int   intx8    __attribute__((ext_vector_type(8)));
typedef float floatx16 __attribute__((ext_vector_type(16)));
typedef float floatx2  __attribute__((ext_vector_type(2)));

// triu_indices(16, 1)
__constant__ unsigned char c_I[120] = {
    0,0,0,0,0,0,0,0,0,0,0,0,0,0,0,
    1,1,1,1,1,1,1,1,1,1,1,1,1,1,
    2,2,2,2,2,2,2,2,2,2,2,2,2,
    3,3,3,3,3,3,3,3,3,3,3,3,
    4,4,4,4,4,4,4,4,4,4,4,
    5,5,5,5,5,5,5,5,5,5,
    6,6,6,6,6,6,6,6,6,
    7,7,7,7,7,7,7,7,
    8,8,8,8,8,8,8,
    9,9,9,9,9,9,
    10,10,10,10,10,
    11,11,11,11,
    12,12,12,
    13,13,
    14
};
__constant__ unsigned char c_J[120] = {
    1,2,3,4,5,6,7,8,9,10,11,12,13,14,15,
    2,3,4,5,6,7,8,9,10,11,12,13,14,15,
    3,4,5,6,7,8,9,10,11,12,13,14,15,
    4,5,6,7,8,9,10,11,12,13,14,15,
    5,6,7,8,9,10,11,12,13,14,15,
    6,7,8,9,10,11,12,13,14,15,
    7,8,9,10,11,12,13,14,15,
    8,9,10,11,12,13,14,15,
    9,10,11,12,13,14,15,
    10,11,12,13,14,15,
    11,12,13,14,15,
    12,13,14,15,
    13,14,15,
    14,15,
    15
};

__device__ __forceinline__ float ssp(float x) {
    float a = fabsf(x);
    return fmaxf(x, 0.0f) + log1pf(__expf(-a)) - 0.69314718056f;
}
__device__ __forceinline__ float redg(float v) {
    v += __shfl_xor(v, 1);
    v += __shfl_xor(v, 2);
    v += __shfl_xor(v, 4);
    return v;
}

// ---------------------------------------------------------------------------
// Prep (verified R14): W1 -> fp8 e4m3 (pre-scaled 2^6; MFMA applies 2^-6 via
// scale_b) in 32x32x64 B-fragment order.
// ---------------------------------------------------------------------------
__global__ __launch_bounds__(256)
void prep_w1_kernel(const float* __restrict__ W1, intx8* __restrict__ ws)
{
    __shared__ float w[2 * N_FEATS * HIDDEN];   // 16 KB: two pairs' rows
    const int t = blockIdx.x;
    const float* src = W1 + (size_t)(2 * t) * (N_FEATS * HIDDEN);
    for (int k = threadIdx.x; k < 2 * N_FEATS * HIDDEN; k += 256) w[k] = src[k];
    __syncthreads();

    const int tid = threadIdx.x;
    if (tid >= 128) return;
    const int lane = tid & 63;
    const int nh   = tid >> 6;
    const int lh   = lane >> 5;
    const int col  = nh * 32 + (lane & 31);
    const int fb   = lh * 16;
    intx8 frag;
#pragma unroll
    for (int r = 0; r < 8; ++r) {
        const int pair = r >> 2;
        const int fo   = fb + ((r & 3) << 2);
        const float v0 = 64.0f * w[(pair * N_FEATS + fo + 0) * 64 + col];
        const float v1 = 64.0f * w[(pair * N_FEATS + fo + 1) * 64 + col];
        const float v2 = 64.0f * w[(pair * N_FEATS + fo + 2) * 64 + col];
        const float v3 = 64.0f * w[(pair * N_FEATS + fo + 3) * 64 + col];
        int d = __builtin_amdgcn_cvt_pk_fp8_f32(v0, v1, 0, false);
        d     = __builtin_amdgcn_cvt_pk_fp8_f32(v2, v3, d, true);
        frag[r] = d;
    }
    ws[(size_t)(t * 2 + nh) * 64 + lane] = frag;
}

// ---------------------------------------------------------------------------
// Kernel 1 — GEMM ONLY (R15 split): phases 1-2 + fp8 K-loop, wave dumps raw
// 32x64 partial to global.
// R16: feature byte built directly as e4m3 bit pattern: byte = sat(56.5-t'^2),
// t' = sqrt(8 log2 e)(d-mu)/sigma. Passed with absmax 0.
// R17/R18: same math, fewer instructions:
//   - v_pk_fma_f32 (dual-pipe packed fp32: 2 feats/inst) for t and s=t*t-56.5
//   - v_cvt_pk_u8_f32 with -src modifier: clamp+convert+byte-insert in ONE op
// ---------------------------------------------------------------------------
__global__ __launch_bounds__(BLOCK)
void wfnet_gemm(const float* __restrict__ rs,
                const float* __restrict__ coords,
                const intx8* __restrict__ ws,
                float* __restrict__ partials)
{
    __shared__ float lds_rs[TB * N_EL * 3];   // 6 KB
    __shared__ float lds_dist[TB * DLD];      // 23.7 KB

    const int tid  = threadIdx.x;
    const int wave = tid >> 6;               // = kh
    const int lane = tid & 63;
    const int m    = lane & 31;
    const int lh   = lane >> 5;

    // ---- phase 1: stage rs ----
    {
        const float* rs_blk = rs + (size_t)blockIdx.x * (TB * N_EL * 3);
        for (int k = tid; k < TB * N_EL * 3; k += BLOCK) lds_rs[k] = rs_blk[k];
    }
    __syncthreads();

    // ---- phase 2: distances only ----
    {
        const int bl = tid >> 3, g = tid & 7;
        const float* myrs = lds_rs + bl * (N_EL * 3);
        float* dst = lds_dist + bl * DLD;
        for (int i = 0; i < 8; ++i) {
            const int p = g + 8 * i;
            const int e = p >> 2, n = p & 3;
            const float dx = myrs[e * 3 + 0] - coords[n * 3 + 0];
            const float dy = myrs[e * 3 + 1] - coords[n * 3 + 1];
            const float dz = myrs[e * 3 + 2] - coords[n * 3 + 2];
            dst[p] = sqrtf(dx * dx + dy * dy + dz * dz);
        }
        for (int i = 0; i < 15; ++i) {
            const int q  = g + 8 * i;
            const int ei = 3 * (int)c_I[q], ej = 3 * (int)c_J[q];
            const float dx = myrs[ei + 0] - myrs[ej + 0];
            const float dy = myrs[ei + 1] - myrs[ej + 1];
            const float dz = myrs[ei + 2] - myrs[ej + 2];
            dst[64 + q] = sqrtf(dx * dx + dy * dy + dz * dz);
        }
    }
    __syncthreads();

    // per-lane packed Gaussian constants for feature pairs (f0+2i, f0+2i+1)
    // P1 = sqrt(8*log2 e)/sigma; byte = sat_u8(56.5 - (d*P1+P0)^2)
    const int f0 = lh * 16;
#define MKC2(P, FA) floatx2 P##1, P##0; { \
    const float fqa = (float)(FA)     * (1.0f / 31.0f); \
    const float fqb = (float)((FA)+1) * (1.0f / 31.0f); \
    const float p1a = (7.0f / (1.0f + 10.0f * fqa)) * 3.3972871404442143f; \
    const float p1b = (7.0f / (1.0f + 10.0f * fqb)) * 3.3972871404442143f; \
    P##1[0] = p1a; P##1[1] = p1b; \
    P##0[0] = -10.0f * fqa * fqa * p1a; \
    P##0[1] = -10.0f * fqb * fqb * p1b; }
    MKC2(G0_, f0 + 0)  MKC2(G1_, f0 + 2)  MKC2(G2_, f0 + 4)  MKC2(G3_, f0 + 6)
    MKC2(G4_, f0 + 8)  MKC2(G5_, f0 + 10) MKC2(G6_, f0 + 12) MKC2(G7_, f0 + 14)
#undef MKC2
    const floatx2 mC56 = {-56.5f, -56.5f};   // s = t*t - 56.5; byte = sat(-s)

    floatx16 accA = {};
    floatx16 accB = {};
    const intx8* wq = ws + ((size_t)(wave * TPW) * 128 + lane);
    const float* drow = lds_dist + m * DLD + wave * (2 * TPW);

    // s = t^2 - 56.5 for a feature pair (packed fp32, 2 insts / 2 feats)
#define SQ2(dd2, P1, P0) ({ floatx2 t2_, s2_; \
    asm("v_pk_fma_f32 %0, %1, %2, %3" : "=v"(t2_) : "v"(dd2), "v"(P1), "v"(P0)); \
    asm("v_pk_fma_f32 %0, %1, %1, %2" : "=v"(s2_) : "v"(t2_), "v"(mC56)); \
    s2_; })
    // one dword = 4 feature bytes; v_cvt_pk_u8_f32 clamps & inserts byte
#define PKD(dd2, Pa1, Pa0, Pb1, Pb0) ({ \
    const floatx2 sa_ = SQ2(dd2, Pa1, Pa0); \
    const floatx2 sb_ = SQ2(dd2, Pb1, Pb0); \
    unsigned w_; \
    asm("v_cvt_pk_u8_f32 %0, -%1, 0, 0"  : "=v"(w_) : "v"(sa_[0])); \
    asm("v_cvt_pk_u8_f32 %0, -%1, 1, %0" : "+v"(w_) : "v"(sa_[1])); \
    asm("v_cvt_pk_u8_f32 %0, -%1, 2, %0" : "+v"(w_) : "v"(sb_[0])); \
    asm("v_cvt_pk_u8_f32 %0, -%1, 3, %0" : "+v"(w_) : "v"(sb_[1])); \
    (int)w_; })
#define MKA8(AV, dx0, dx1) \
    intx8 AV; { \
    const floatx2 d20 = {dx0, dx0}; \
    const floatx2 d21 = {dx1, dx1}; \
    AV[0] = PKD(d20, G0_1, G0_0, G1_1, G1_0); \
    AV[1] = PKD(d20, G2_1, G2_0, G3_1, G3_0); \
    AV[2] = PKD(d20, G4_1, G4_0, G5_1, G5_0); \
    AV[3] = PKD(d20, G6_1, G6_0, G7_1, G7_0); \
    AV[4] = PKD(d21, G0_1, G0_0, G1_1, G1_0); \
    AV[5] = PKD(d21, G2_1, G2_0, G3_1, G3_0); \
    AV[6] = PKD(d21, G4_1, G4_0, G5_1, G5_0); \
    AV[7] = PKD(d21, G6_1, G6_0, G7_1, G7_0); }
#define KROUND(AV, Q0, Q1) { \
    accA = __builtin_amdgcn_mfma_scale_f32_32x32x64_f8f6f4( \
               AV, Q0, accA, 0, 0, 0, 0x7F7F7F7F, 0, 0x79797979); \
    accB = __builtin_amdgcn_mfma_scale_f32_32x32x64_f8f6f4( \
               AV, Q1, accB, 0, 0, 0, 0x7F7F7F7F, 0, 0x79797979); }

    intx8 pA0 = wq[0],   pA1 = wq[64];
    intx8 pB0 = wq[128], pB1 = wq[192];
    float dA0 = drow[0], dA1 = drow[1];
    float dB0 = drow[2], dB1 = drow[3];

    for (int it = 0; it < 10; ++it) {
        const intx8* wn = wq + 256;
        const float eA0 = drow[4 * it + 4], eA1 = drow[4 * it + 5];
        const float eB0 = drow[4 * it + 6], eB1 = drow[4 * it + 7];

        { MKA8(av, dA0, dA1) KROUND(av, pA0, pA1) }
        pA0 = wn[0]; pA1 = wn[64];

        { MKA8(bv, dB0, dB1) KROUND(bv, pB0, pB1) }
        pB0 = wn[128]; pB1 = wn[192];

        wq = wn;
        dA0 = eA0; dA1 = eA1; dB0 = eB0; dB1 = eB1;
    }
    {
        const intx8* wn = wq + 256;
        const float eA0 = drow[44], eA1 = drow[45];
        { MKA8(av, dA0, dA1) KROUND(av, pA0, pA1) }
        pA0 = wn[0]; pA1 = wn[64];
        { MKA8(bv, dB0, dB1) KROUND(bv, pB0, pB1) }
        { MKA8(cv, eA0, eA1) KROUND(cv, pA0, pA1) }
    }
#undef KROUND
#undef MKA8
#undef PKD
#undef SQ2

    // ---- dump raw partial to global, no barrier. C/D layout:
    //      col = lane&31 (+32 for B), row el = (rg&3) + 8*(rg>>2) + 4*lh ----
    float* pdst = partials + ((size_t)blockIdx.x * 4 + wave) * 2048;
#pragma unroll
    for (int rg = 0; rg < 16; ++rg) {
        const int el = (rg & 3) + 8 * (rg >> 2) + 4 * lh;
        pdst[el * 64 + m]      = accA[rg];
        pdst[el * 64 + 32 + m] = accB[rg];
    }
}

// ---------------------------------------------------------------------------
// Kernel 2 — tail: sum 4 partials + b1 + ssp -> h1 (LDS) -> layers 2/3 +
// asy + output. R17: W2 staged in LDS (16 KB) instead of chip-wide L1/L2
// re-reads; ds_read_b128 pattern is 2-way conflict = free.
// ---------------------------------------------------------------------------
__global__ __launch_bounds__(BLOCK)
void wfnet_tail(const float* __restrict__ rs,
                const float* __restrict__ coords,
                const float* __restrict__ charges,
                const float* __restrict__ partials,
                const float* __restrict__ b1,
                const float* __restrict__ W2,
                const float* __restrict__ b2,
                const float* __restrict__ W3,
                const float* __restrict__ b3,
                float* __restrict__ out)
{
    __shared__ float lds_rs[TB * N_EL * 3];   // 6 KB
    __shared__ float lds_h1[TB * H1LD];       // 8.7 KB
    __shared__ float lds_w2[HIDDEN * HIDDEN]; // 16 KB

    const int tid = threadIdx.x;
    const int el  = tid >> 3;                // 0..31
    const int g   = tid & 7;
    const int b   = blockIdx.x * TB + el;

    // stage rs for asy
    {
        const float* rs_blk = rs + (size_t)blockIdx.x * (TB * N_EL * 3);
        for (int k = tid; k < TB * N_EL * 3; k += BLOCK) lds_rs[k] = rs_blk[k];
    }
    // stage W2 (4 float4 per thread)
    {
        float4* dst = (float4*)lds_w2;
        const float4* src = (const float4*)W2;
#pragma unroll
        for (int i = 0; i < 4; ++i) dst[tid + 256 * i] = src[tid + 256 * i];
    }

    // sum 4 wave-partials for (el, cols g*8..g*8+7), + b1, ssp -> LDS h1
    {
        const float* pb = partials + (size_t)blockIdx.x * 8192 + el * 64 + g * 8;
        const float4 p00 = ((const float4*)(pb + 0 * 2048))[0];
        const float4 p01 = ((const float4*)(pb + 0 * 2048))[1];
        const float4 p10 = ((const float4*)(pb + 1 * 2048))[0];
        const float4 p11 = ((const float4*)(pb + 1 * 2048))[1];
        const float4 p20 = ((const float4*)(pb + 2 * 2048))[0];
        const float4 p21 = ((const float4*)(pb + 2 * 2048))[1];
        const float4 p30 = ((const float4*)(pb + 3 * 2048))[0];
        const float4 p31 = ((const float4*)(pb + 3 * 2048))[1];
        const float4 ba = ((const float4*)(b1 + g * 8))[0];
        const float4 bb = ((const float4*)(b1 + g * 8))[1];
        float* h1w = lds_h1 + el * H1LD + g * 8;
        h1w[0] = ssp(p00.x + p10.x + p20.x + p30.x + ba.x);
        h1w[1] = ssp(p00.y + p10.y + p20.y + p30.y + ba.y);
        h1w[2] = ssp(p00.z + p10.z + p20.z + p30.z + ba.z);
        h1w[3] = ssp(p00.w + p10.w + p20.w + p30.w + ba.w);
        h1w[4] = ssp(p01.x + p11.x + p21.x + p31.x + bb.x);
        h1w[5] = ssp(p01.y + p11.y + p21.y + p31.y + bb.y);
        h1w[6] = ssp(p01.z + p11.z + p21.z + p31.z + bb.z);
        h1w[7] = ssp(p01.w + p11.w + p21.w + p31.w + bb.w);
    }

    // asy partial: this thread's 8 el-nuc pairs (needs only lds_rs)
    float asy = 0.0f;
    __syncthreads();   // rs + W2 staged AND h1 visible
    {
        const float* myrs = lds_rs + el * (N_EL * 3);
        const float4 ch = *(const float4*)charges;
#pragma unroll
        for (int i = 0; i < 8; ++i) {
            const int p = g + 8 * i;
            const int e = p >> 2, n = p & 3;
            const float dx = myrs[e * 3 + 0] - coords[n * 3 + 0];
            const float dy = myrs[e * 3 + 1] - coords[n * 3 + 1];
            const float dz = myrs[e * 3 + 2] - coords[n * 3 + 2];
            const float d = sqrtf(dx * dx + dy * dy + dz * dz);
            const float Z = (n < 2) ? ((n == 0) ? ch.x : ch.y)
                                    : ((n == 2) ? ch.z : ch.w);
            asy += (Z * d + d * d) / (1.0f + d);   // decay = sqrt(2*0.5) = 1
        }
    }
    asy = redg(asy);

    // layers 2/3 (W2 from LDS)
    const float4* __restrict__ W2v = (const float4*)lds_w2;
    const float4* __restrict__ b2v = (const float4*)b2;
    const int wbi = g * 2;
    const float4 b2a = b2v[wbi], b2b = b2v[wbi + 1];
    float s0 = b2a.x, s1 = b2a.y, s2 = b2a.z, s3 = b2a.w;
    float s4 = b2b.x, s5 = b2b.y, s6 = b2b.z, s7 = b2b.w;

    const float* __restrict__ h1row = lds_h1 + el * H1LD;
    for (int k = 0; k < HIDDEN; ++k) {
        const float hk  = h1row[k];
        const float4 wa = W2v[k * 16 + wbi];
        const float4 wb = W2v[k * 16 + wbi + 1];
        s0 = fmaf(hk, wa.x, s0); s1 = fmaf(hk, wa.y, s1);
        s2 = fmaf(hk, wa.z, s2); s3 = fmaf(hk, wa.w, s3);
        s4 = fmaf(hk, wb.x, s4); s5 = fmaf(hk, wb.y, s5);
        s6 = fmaf(hk, wb.z, s6); s7 = fmaf(hk, wb.w, s7);
    }

    const float4* __restrict__ W3v = (const float4*)W3;
    const float4 w3a = W3v[wbi], w3b = W3v[wbi + 1];
    float part = ssp(s0) * w3a.x + ssp(s1) * w3a.y
               + ssp(s2) * w3a.z + ssp(s3) * w3a.w
               + ssp(s4) * w3b.x + ssp(s5) * w3b.y
               + ssp(s6) * w3b.z + ssp(s7) * w3b.w;
    part = redg(part);

    if (g == 0) {
        const float ys = part + b3[0];
        out[b] = __expf(ys) * __expf(-asy);
    }
}

extern "C" void kernel_launch(void* const* d_in, const int* in_sizes, int n_in,
                              void* d_out, int out_size, void* d_ws, size_t ws_size,
                              hipStream_t stream) {
    const float* rs      = (const float*)d_in[0];
    const float* coords  = (const float*)d_in[1];
    const float* charges = (const float*)d_in[2];
    const float* W1      = (const float*)d_in[3];
    const float* b1      = (const float*)d_in[4];
    const float* W2      = (const float*)d_in[5];
    const float* b2      = (const float*)d_in[6];
    const float* W3      = (const float*)d_in[7];
    const float* b3      = (const float*)d_in[8];
    float* out = (float*)d_out;

    const int batch = in_sizes[0] / (N_EL * 3);   // 32768
    intx8* w1f8     = (intx8*)d_ws;               // 368 KB fp8 W1
    float* partials = (float*)((char*)d_ws + WS_PART_OFF);  // 32 MB

    prep_w1_kernel<<<N_PAIRS / 2, 256, 0, stream>>>(W1, w1f8);
    wfnet_gemm<<<batch / TB, BLOCK, 0, stream>>>(rs, coords, w1f8, partials);
    wfnet_tail<<<batch / TB, BLOCK, 0, stream>>>(rs, coords, charges, partials,
                                                 b1, W2, b2, W3, b3, out);
}

// Round 4
// 129.116 us; speedup vs baseline: 1.1313x; 1.0118x over previous
//
#include <hip/hip_runtime.h>
#include <math.h>

#define N_EL    16
#define N_NUC   4
#define N_FEATS 32
#define N_PAIRS 184
#define HIDDEN  64
#define TB      32           // batch elements per block
#define BLOCK   256
#define DLD     185          // dist LDS stride
#define H1LD    68           // h1 stride in kernel 2
#define TPW     23           // K-tiles (2 pairs each) per wave; 4*23*2 = 184
#define WS_PART_OFF (1 << 19)   // partials start at 512 KB into d_ws

typedef int   intx8    __attribute__((ext_vector_type(8)));
typedef float floatx16 __attribute__((ext_vector_type(16)));

// triu_indices(16, 1)
__constant__ unsigned char c_I[120] = {
    0,0,0,0,0,0,0,0,0,0,0,0,0,0,0,
    1,1,1,1,1,1,1,1,1,1,1,1,1,1,
    2,2,2,2,2,2,2,2,2,2,2,2,2,
    3,3,3,3,3,3,3,3,3,3,3,3,
    4,4,4,4,4,4,4,4,4,4,4,
    5,5,5,5,5,5,5,5,5,5,
    6,6,6,6,6,6,6,6,6,
    7,7,7,7,7,7,7,7,
    8,8,8,8,8,8,8,
    9,9,9,9,9,9,
    10,10,10,10,10,
    11,11,11,11,
    12,12,12,
    13,13,
    14
};
__constant__ unsigned char c_J[120] = {
    1,2,3,4,5,6,7,8,9,10,11,12,13,14,15,
    2,3,4,5,6,7,8,9,10,11,12,13,14,15,
    3,4,5,6,7,8,9,10,11,12,13,14,15,
    4,5,6,7,8,9,10,11,12,13,14,15,
    5,6,7,8,9,10,11,12,13,14,15,
    6,7,8,9,10,11,12,13,14,15,
    7,8,9,10,11,12,13,14,15,
    8,9,10,11,12,13,14,15,
    9,10,11,12,13,14,15,
    10,11,12,13,14,15,
    11,12,13,14,15,
    12,13,14,15,
    13,14,15,
    14,15,
    15
};

__device__ __forceinline__ float ssp(float x) {
    float a = fabsf(x);
    return fmaxf(x, 0.0f) + log1pf(__expf(-a)) - 0.69314718056f;
}
__device__ __forceinline__ float redg(float v) {
    v += __shfl_xor(v, 1);
    v += __shfl_xor(v, 2);
    v += __shfl_xor(v, 4);
    return v;
}

// ---------------------------------------------------------------------------
// Prep (verified R14): W1 -> fp8 e4m3 (pre-scaled 2^6; MFMA applies 2^-6 via
// scale_b) in 32x32x64 B-fragment order.
// ---------------------------------------------------------------------------
__global__ __launch_bounds__(256)
void prep_w1_kernel(const float* __restrict__ W1, intx8* __restrict__ ws)
{
    __shared__ float w[2 * N_FEATS * HIDDEN];   // 16 KB: two pairs' rows
    const int t = blockIdx.x;
    const float* src = W1 + (size_t)(2 * t) * (N_FEATS * HIDDEN);
    for (int k = threadIdx.x; k < 2 * N_FEATS * HIDDEN; k += 256) w[k] = src[k];
    __syncthreads();

    const int tid = threadIdx.x;
    if (tid >= 128) return;
    const int lane = tid & 63;
    const int nh   = tid >> 6;
    const int lh   = lane >> 5;
    const int col  = nh * 32 + (lane & 31);
    const int fb   = lh * 16;
    intx8 frag;
#pragma unroll
    for (int r = 0; r < 8; ++r) {
        const int pair = r >> 2;
        const int fo   = fb + ((r & 3) << 2);
        const float v0 = 64.0f * w[(pair * N_FEATS + fo + 0) * 64 + col];
        const float v1 = 64.0f * w[(pair * N_FEATS + fo + 1) * 64 + col];
        const float v2 = 64.0f * w[(pair * N_FEATS + fo + 2) * 64 + col];
        const float v3 = 64.0f * w[(pair * N_FEATS + fo + 3) * 64 + col];
        int d = __builtin_amdgcn_cvt_pk_fp8_f32(v0, v1, 0, false);
        d     = __builtin_amdgcn_cvt_pk_fp8_f32(v2, v3, d, true);
        frag[r] = d;
    }
    ws[(size_t)(t * 2 + nh) * 64 + lane] = frag;
}

// ---------------------------------------------------------------------------
// Kernel 1 — GEMM ONLY: phases 1-2 + fp8 K-loop, wave dumps raw 32x64 partial.
// R16: feature byte = e4m3 bit pattern sat(56.5 - t'^2), t' = sqrt(8 log2 e)
//      (d-mu)/sigma. HW-validated (absmax 0).
// R18: v_cvt_pk_u8_f32 validated on HW, but asm pinning + tied-operand chains
//      made the kernel latency-bound (VALU 66->33% yet wall up). R19: same
//      math via BUILTINS + plain fmaf so LLVM can interleave feature-gen with
//      MFMAs and drow prefetch. 3 VALU/feature: fma, fma(-t,t,56.5), cvt_pk_u8.
// ---------------------------------------------------------------------------
__global__ __launch_bounds__(BLOCK)
void wfnet_gemm(const float* __restrict__ rs,
                const float* __restrict__ coords,
                const intx8* __restrict__ ws,
                float* __restrict__ partials)
{
    __shared__ float lds_rs[TB * N_EL * 3];   // 6 KB
    __shared__ float lds_dist[TB * DLD];      // 23.7 KB

    const int tid  = threadIdx.x;
    const int wave = tid >> 6;               // = kh
    const int lane = tid & 63;
    const int m    = lane & 31;
    const int lh   = lane >> 5;

    // ---- phase 1: stage rs ----
    {
        const float* rs_blk = rs + (size_t)blockIdx.x * (TB * N_EL * 3);
        for (int k = tid; k < TB * N_EL * 3; k += BLOCK) lds_rs[k] = rs_blk[k];
    }
    __syncthreads();

    // ---- phase 2: distances only ----
    {
        const int bl = tid >> 3, g = tid & 7;
        const float* myrs = lds_rs + bl * (N_EL * 3);
        float* dst = lds_dist + bl * DLD;
        for (int i = 0; i < 8; ++i) {
            const int p = g + 8 * i;
            const int e = p >> 2, n = p & 3;
            const float dx = myrs[e * 3 + 0] - coords[n * 3 + 0];
            const float dy = myrs[e * 3 + 1] - coords[n * 3 + 1];
            const float dz = myrs[e * 3 + 2] - coords[n * 3 + 2];
            dst[p] = sqrtf(dx * dx + dy * dy + dz * dz);
        }
        for (int i = 0; i < 15; ++i) {
            const int q  = g + 8 * i;
            const int ei = 3 * (int)c_I[q], ej = 3 * (int)c_J[q];
            const float dx = myrs[ei + 0] - myrs[ej + 0];
            const float dy = myrs[ei + 1] - myrs[ej + 1];
            const float dz = myrs[ei + 2] - myrs[ej + 2];
            dst[64 + q] = sqrtf(dx * dx + dy * dy + dz * dz);
        }
    }
    __syncthreads();

    // per-lane Gaussian constants for feats lh*16 .. lh*16+15
    // P1 = sqrt(8*log2 e)/sigma; byte = sat_u8(56.5 - (d*P1+P0)^2)
    const int f0 = lh * 16;
#define MKC(P, FF) float P##1, P##0; { \
    const float fq = (float)(FF) * (1.0f / 31.0f); \
    const float mu = 10.0f * fq * fq; \
    const float is = 7.0f / (1.0f + 10.0f * fq); \
    P##1 = is * 3.3972871404442143f; \
    P##0 = -mu * P##1; }
    MKC(F0_,  f0 + 0)  MKC(F1_,  f0 + 1)  MKC(F2_,  f0 + 2)  MKC(F3_,  f0 + 3)
    MKC(F4_,  f0 + 4)  MKC(F5_,  f0 + 5)  MKC(F6_,  f0 + 6)  MKC(F7_,  f0 + 7)
    MKC(F8_,  f0 + 8)  MKC(F9_,  f0 + 9)  MKC(F10_, f0 + 10) MKC(F11_, f0 + 11)
    MKC(F12_, f0 + 12) MKC(F13_, f0 + 13) MKC(F14_, f0 + 14) MKC(F15_, f0 + 15)
#undef MKC

    floatx16 accA = {};
    floatx16 accB = {};
    const intx8* wq = ws + ((size_t)(wave * TPW) * 128 + lane);
    const float* drow = lds_dist + m * DLD + wave * (2 * TPW);

    // z = 56.5 - t^2 (>=0 only near the Gaussian center; cvt clamps the rest)
#define XZ(dd, P) ({ const float t_ = fmaf(dd, P##1, P##0); fmaf(t_, -t_, 56.5f); })
    // one dword = 4 feature bytes; builtin cvt_pk_u8 clamps & inserts byte,
    // and stays visible to the instruction scheduler (no asm pinning).
#define PKD(dd, A, B, C, D) ({ \
    unsigned w_; \
    w_ = __builtin_amdgcn_cvt_pk_u8_f32(XZ(dd, A), 0, 0u); \
    w_ = __builtin_amdgcn_cvt_pk_u8_f32(XZ(dd, B), 1, w_); \
    w_ = __builtin_amdgcn_cvt_pk_u8_f32(XZ(dd, C), 2, w_); \
    w_ = __builtin_amdgcn_cvt_pk_u8_f32(XZ(dd, D), 3, w_); \
    (int)w_; })
#define MKA8(AV, dx0, dx1) \
    intx8 AV; { \
    AV[0] = PKD(dx0, F0_,  F1_,  F2_,  F3_);  \
    AV[1] = PKD(dx0, F4_,  F5_,  F6_,  F7_);  \
    AV[2] = PKD(dx0, F8_,  F9_,  F10_, F11_); \
    AV[3] = PKD(dx0, F12_, F13_, F14_, F15_); \
    AV[4] = PKD(dx1, F0_,  F1_,  F2_,  F3_);  \
    AV[5] = PKD(dx1, F4_,  F5_,  F6_,  F7_);  \
    AV[6] = PKD(dx1, F8_,  F9_,  F10_, F11_); \
    AV[7] = PKD(dx1, F12_, F13_, F14_, F15_); }
#define KROUND(AV, Q0, Q1) { \
    accA = __builtin_amdgcn_mfma_scale_f32_32x32x64_f8f6f4( \
               AV, Q0, accA, 0, 0, 0, 0x7F7F7F7F, 0, 0x79797979); \
    accB = __builtin_amdgcn_mfma_scale_f32_32x32x64_f8f6f4( \
               AV, Q1, accB, 0, 0, 0, 0x7F7F7F7F, 0, 0x79797979); }

    intx8 pA0 = wq[0],   pA1 = wq[64];
    intx8 pB0 = wq[128], pB1 = wq[192];
    float dA0 = drow[0], dA1 = drow[1];
    float dB0 = drow[2], dB1 = drow[3];

    for (int it = 0; it < 10; ++it) {
        const intx8* wn = wq + 256;
        const float eA0 = drow[4 * it + 4], eA1 = drow[4 * it + 5];
        const float eB0 = drow[4 * it + 6], eB1 = drow[4 * it + 7];

        { MKA8(av, dA0, dA1) KROUND(av, pA0, pA1) }
        pA0 = wn[0]; pA1 = wn[64];

        { MKA8(bv, dB0, dB1) KROUND(bv, pB0, pB1) }
        pB0 = wn[128]; pB1 = wn[192];

        wq = wn;
        dA0 = eA0; dA1 = eA1; dB0 = eB0; dB1 = eB1;
    }
    {
        const intx8* wn = wq + 256;
        const float eA0 = drow[44], eA1 = drow[45];
        { MKA8(av, dA0, dA1) KROUND(av, pA0, pA1) }
        pA0 = wn[0]; pA1 = wn[64];
        { MKA8(bv, dB0, dB1) KROUND(bv, pB0, pB1) }
        { MKA8(cv, eA0, eA1) KROUND(cv, pA0, pA1) }
    }
#undef KROUND
#undef MKA8
#undef PKD
#undef XZ

    // ---- dump raw partial to global, no barrier. C/D layout:
    //      col = lane&31 (+32 for B), row el = (rg&3) + 8*(rg>>2) + 4*lh ----
    float* pdst = partials + ((size_t)blockIdx.x * 4 + wave) * 2048;
#pragma unroll
    for (int rg = 0; rg < 16; ++rg) {
        const int el = (rg & 3) + 8 * (rg >> 2) + 4 * lh;
        pdst[el * 64 + m]      = accA[rg];
        pdst[el * 64 + 32 + m] = accB[rg];
    }
}

// ---------------------------------------------------------------------------
// Kernel 2 — tail: sum 4 partials + b1 + ssp -> h1 (LDS) -> layers 2/3 +
// asy + output. R17: W2 staged in LDS (16 KB); ds_read_b128 2-way = free.
// ---------------------------------------------------------------------------
__global__ __launch_bounds__(BLOCK)
void wfnet_tail(const float* __restrict__ rs,
                const float* __restrict__ coords,
                const float* __restrict__ charges,
                const float* __restrict__ partials,
                const float* __restrict__ b1,
                const float* __restrict__ W2,
                const float* __restrict__ b2,
                const float* __restrict__ W3,
                const float* __restrict__ b3,
                float* __restrict__ out)
{
    __shared__ float lds_rs[TB * N_EL * 3];   // 6 KB
    __shared__ float lds_h1[TB * H1LD];       // 8.7 KB
    __shared__ float lds_w2[HIDDEN * HIDDEN]; // 16 KB

    const int tid = threadIdx.x;
    const int el  = tid >> 3;                // 0..31
    const int g   = tid & 7;
    const int b   = blockIdx.x * TB + el;

    // stage rs for asy
    {
        const float* rs_blk = rs + (size_t)blockIdx.x * (TB * N_EL * 3);
        for (int k = tid; k < TB * N_EL * 3; k += BLOCK) lds_rs[k] = rs_blk[k];
    }
    // stage W2 (4 float4 per thread)
    {
        float4* dst = (float4*)lds_w2;
        const float4* src = (const float4*)W2;
#pragma unroll
        for (int i = 0; i < 4; ++i) dst[tid + 256 * i] = src[tid + 256 * i];
    }

    // sum 4 wave-partials for (el, cols g*8..g*8+7), + b1, ssp -> LDS h1
    {
        const float* pb = partials + (size_t)blockIdx.x * 8192 + el * 64 + g * 8;
        const float4 p00 = ((const float4*)(pb + 0 * 2048))[0];
        const float4 p01 = ((const float4*)(pb + 0 * 2048))[1];
        const float4 p10 = ((const float4*)(pb + 1 * 2048))[0];
        const float4 p11 = ((const float4*)(pb + 1 * 2048))[1];
        const float4 p20 = ((const float4*)(pb + 2 * 2048))[0];
        const float4 p21 = ((const float4*)(pb + 2 * 2048))[1];
        const float4 p30 = ((const float4*)(pb + 3 * 2048))[0];
        const float4 p31 = ((const float4*)(pb + 3 * 2048))[1];
        const float4 ba = ((const float4*)(b1 + g * 8))[0];
        const float4 bb = ((const float4*)(b1 + g * 8))[1];
        float* h1w = lds_h1 + el * H1LD + g * 8;
        h1w[0] = ssp(p00.x + p10.x + p20.x + p30.x + ba.x);
        h1w[1] = ssp(p00.y + p10.y + p20.y + p30.y + ba.y);
        h1w[2] = ssp(p00.z + p10.z + p20.z + p30.z + ba.z);
        h1w[3] = ssp(p00.w + p10.w + p20.w + p30.w + ba.w);
        h1w[4] = ssp(p01.x + p11.x + p21.x + p31.x + bb.x);
        h1w[5] = ssp(p01.y + p11.y + p21.y + p31.y + bb.y);
        h1w[6] = ssp(p01.z + p11.z + p21.z + p31.z + bb.z);
        h1w[7] = ssp(p01.w + p11.w + p21.w + p31.w + bb.w);
    }

    // asy partial: this thread's 8 el-nuc pairs (needs only lds_rs)
    float asy = 0.0f;
    __syncthreads();   // rs + W2 staged AND h1 visible
    {
        const float* myrs = lds_rs + el * (N_EL * 3);
        const float4 ch = *(const float4*)charges;
#pragma unroll
        for (int i = 0; i < 8; ++i) {
            const int p = g + 8 * i;
            const int e = p >> 2, n = p & 3;
            const float dx = myrs[e * 3 + 0] - coords[n * 3 + 0];
            const float dy = myrs[e * 3 + 1] - coords[n * 3 + 1];
            const float dz = myrs[e * 3 + 2] - coords[n * 3 + 2];
            const float d = sqrtf(dx * dx + dy * dy + dz * dz);
            const float Z = (n < 2) ? ((n == 0) ? ch.x : ch.y)
                                    : ((n == 2) ? ch.z : ch.w);
            asy += (Z * d + d * d) / (1.0f + d);   // decay = sqrt(2*0.5) = 1
        }
    }
    asy = redg(asy);

    // layers 2/3 (W2 from LDS)
    const float4* __restrict__ W2v = (const float4*)lds_w2;
    const float4* __restrict__ b2v = (const float4*)b2;
    const int wbi = g * 2;
    const float4 b2a = b2v[wbi], b2b = b2v[wbi + 1];
    float s0 = b2a.x, s1 = b2a.y, s2 = b2a.z, s3 = b2a.w;
    float s4 = b2b.x, s5 = b2b.y, s6 = b2b.z, s7 = b2b.w;

    const float* __restrict__ h1row = lds_h1 + el * H1LD;
    for (int k = 0; k < HIDDEN; ++k) {
        const float hk  = h1row[k];
        const float4 wa = W2v[k * 16 + wbi];
        const float4 wb = W2v[k * 16 + wbi + 1];
        s0 = fmaf(hk, wa.x, s0); s1 = fmaf(hk, wa.y, s1);
        s2 = fmaf(hk, wa.z, s2); s3 = fmaf(hk, wa.w, s3);
        s4 = fmaf(hk, wb.x, s4); s5 = fmaf(hk, wb.y, s5);
        s6 = fmaf(hk, wb.z, s6); s7 = fmaf(hk, wb.w, s7);
    }

    const float4* __restrict__ W3v = (const float4*)W3;
    const float4 w3a = W3v[wbi], w3b = W3v[wbi + 1];
    float part = ssp(s0) * w3a.x + ssp(s1) * w3a.y
               + ssp(s2) * w3a.z + ssp(s3) * w3a.w
               + ssp(s4) * w3b.x + ssp(s5) * w3b.y
               + ssp(s6) * w3b.z + ssp(s7) * w3b.w;
    part = redg(part);

    if (g == 0) {
        const float ys = part + b3[0];
        out[b] = __expf(ys) * __expf(-asy);
    }
}

extern "C" void kernel_launch(void* const* d_in, const int* in_sizes, int n_in,
                              void* d_out, int out_size, void* d_ws, size_t ws_size,
                              hipStream_t stream) {
    const float* rs      = (const float*)d_in[0];
    const float* coords  = (const float*)d_in[1];
    const float* charges = (const float*)d_in[2];
    const float* W1      = (const float*)d_in[3];
    const float* b1      = (const float*)d_in[4];
    const float* W2      = (const float*)d_in[5];
    const float* b2      = (const float*)d_in[6];
    const float* W3      = (const float*)d_in[7];
    const float* b3      = (const float*)d_in[8];
    float* out = (float*)d_out;

    const int batch = in_sizes[0] / (N_EL * 3);   // 32768
    intx8* w1f8     = (intx8*)d_ws;               // 368 KB fp8 W1
    float* partials = (float*)((char*)d_ws + WS_PART_OFF);  // 32 MB

    prep_w1_kernel<<<N_PAIRS / 2, 256, 0, stream>>>(W1, w1f8);
    wfnet_gemm<<<batch / TB, BLOCK, 0, stream>>>(rs, coords, w1f8, partials);
    wfnet_tail<<<batch / TB, BLOCK, 0, stream>>>(rs, coords, charges, partials,
                                                 b1, W2, b2, W3, b3, out);
}